// Round 17
// baseline (11.962 us; speedup 1.0000x reference)
//
#include <hip/hip_runtime.h>
#include <math.h>

#define D 512
#define NREL 512
#define NB 1024

typedef _Float16 f16x8 __attribute__((ext_vector_type(8)));
typedef float f32x4 __attribute__((ext_vector_type(4)));

// tanh(x)/x and atanh(x)/x as even polynomials in u = x^2 (x <= ~0.05 here;
// truncation error < 1e-8, fp32-exact).
__device__ __forceinline__ float tanhc(float u) {
    return 1.0f + u * (-0.33333333f + u * (0.13333333f - u * 0.05396825f));
}
__device__ __forceinline__ float atanhc(float u) {
    return 1.0f + u * (0.33333333f + u * (0.2f + u * 0.14285714f));
}

// diag of one 16x16 tile of (Arows · Brows^T), K = 512, XOR-swizzled LDS rows.
// C/D layout: col = lane&15, row = (lane>>4)*4 + reg  ->  lane holds diag elem
// (col) iff (col>>2) == (lane>>4); that elem is acc[col&3].
__device__ __forceinline__ void diag_gemm(
        const _Float16* __restrict__ Abase, const _Float16* __restrict__ Bbase,
        int rowA, int rowB, float* __restrict__ dst, int lane) {
    const int r15 = lane & 15, kg = lane >> 4;
    const _Float16* pa = Abase + (size_t)(rowA + r15) * 512;
    const _Float16* pb = Bbase + (size_t)(rowB + r15) * 512;
    const int xa = ((rowA + r15) & 7) << 3;
    const int xb = ((rowB + r15) & 7) << 3;
    f32x4 acc = {};
#pragma unroll
    for (int ks = 0; ks < 16; ++ks) {
        const int ko = ks * 32 + kg * 8;
        const f16x8 a = *(const f16x8*)(pa + (ko ^ xa));
        const f16x8 b = *(const f16x8*)(pb + (ko ^ xb));
        acc = __builtin_amdgcn_mfma_f32_16x16x32_f16(a, b, acc, 0, 0, 0);
    }
    if ((r15 >> 2) == kg) dst[r15] = acc[r15 & 3];
}

// Single dispatch, 256 blocks (1/CU), 512 threads. Block = 32m x 64n tile.
// Phase A: ALL 32 global loads issued before any cvt/LDS-store (one latency
// exposure), then stage RAW fp16 (rel, R(s), o) -> swizzled LDS.
// Phase B1: row norms/dots via MFMA self-GEMM diagonals (no shuffles).
// Phase B2: 96-wide scalar chains. Phase B3: dual GEMM + fused epilogue.
__global__ __launch_bounds__(512, 1) void fused_kernel(
        const float* __restrict__ ent, const float* __restrict__ rel,
        const int* __restrict__ trip, const float* __restrict__ grot,
        const float* __restrict__ bias, float* __restrict__ out) {
    extern __shared__ char smem[];
    _Float16* RELs = (_Float16*)smem;            // 64 x 512 fp16 raw (swz)
    _Float16* RTs  = RELs + 64 * 512;            // 32 x 512 fp16 R(s) (swz)
    _Float16* OVs  = RTs + 32 * 512;             // 32 x 512 fp16 o    (swz)
    float* ssA = (float*)(OVs + 32 * 512);       // 32
    float* ooA = ssA + 32;                       // 32
    float* rwA = ooA + 32;                       // 32
    float* uuA = rwA + 32;                       // 64
    float* qas = uuA + 64;                       // 32
    float* qbs = qas + 32;                       // 32
    float* x2s = qbs + 32;                       // 32
    float* esn = x2s + 32;                       // 64
    float* y2n = esn + 64;                       // 64

    const int t = threadIdx.x, wid = t >> 6, lane = t & 63;
    // XCD swizzle (R14-proven): xcd = bid%8 owns a 4n x 8m region
    const int bid = blockIdx.x;
    const int xcd = bid & 7, slot = bid >> 3;
    const int nx  = (xcd & 1) * 4 + (slot & 3);
    const int my  = (xcd >> 1) * 8 + (slot >> 2);
    const int n0 = nx * 64, m0 = my * 32;
    const float c = 0.01f;

    // ---- trip indices first (they gate the ent gather) ----
    int si[4], oi[4];
#pragma unroll
    for (int i = 0; i < 4; ++i) {
        const int b = m0 + wid * 4 + i;
        si[i] = trip[3 * b];
        oi[i] = trip[3 * b + 2];
    }

    // ---- ISSUE ALL 32 GLOBAL LOADS (no dependent ops in between) ----
    float4 ra[8][2], sa[4][2], oa[4][2];
#pragma unroll
    for (int j = 0; j < 8; ++j) {
        const float* p = rel + (size_t)(n0 + wid * 8 + j) * D + lane * 8;
        ra[j][0] = *(const float4*)p;
        ra[j][1] = *(const float4*)(p + 4);
    }
#pragma unroll
    for (int i = 0; i < 4; ++i) {
        const float* ps = ent + (size_t)si[i] * D + lane * 8;
        const float* po = ent + (size_t)oi[i] * D + lane * 8;
        sa[i][0] = *(const float4*)ps;
        sa[i][1] = *(const float4*)(ps + 4);
        oa[i][0] = *(const float4*)po;
        oa[i][1] = *(const float4*)(po + 4);
    }

    // ---- rel: cvt + swizzled LDS store ----
#pragma unroll
    for (int j = 0; j < 8; ++j) {
        const int lr = wid * 8 + j;
        const float4 a0 = ra[j][0], a1 = ra[j][1];
        f16x8 h;
        h[0]=(_Float16)a0.x; h[1]=(_Float16)a0.y; h[2]=(_Float16)a0.z; h[3]=(_Float16)a0.w;
        h[4]=(_Float16)a1.x; h[5]=(_Float16)a1.y; h[6]=(_Float16)a1.z; h[7]=(_Float16)a1.w;
        *(f16x8*)(RELs + lr * 512 + ((lane * 8) ^ ((lr & 7) << 3))) = h;
    }

    // ---- q: rotate raw s; stage R(s), o ----
    const float4 ang = *(const float4*)(grot + 4 * lane);
    const float ca0 = __cosf(ang.x), sa0f = __sinf(ang.x);
    const float ca1 = __cosf(ang.y), sa1f = __sinf(ang.y);
    const float ca2 = __cosf(ang.z), sa2f = __sinf(ang.z);
    const float ca3 = __cosf(ang.w), sa3f = __sinf(ang.w);
#pragma unroll
    for (int i = 0; i < 4; ++i) {
        const float4 s0 = sa[i][0], s1 = sa[i][1];
        const float4 o0 = oa[i][0], o1 = oa[i][1];
        f16x8 hr, ho;
        hr[0] = (_Float16)(ca0 * s0.x - sa0f * s0.y);
        hr[1] = (_Float16)(sa0f * s0.x + ca0 * s0.y);
        hr[2] = (_Float16)(ca1 * s0.z - sa1f * s0.w);
        hr[3] = (_Float16)(sa1f * s0.z + ca1 * s0.w);
        hr[4] = (_Float16)(ca2 * s1.x - sa2f * s1.y);
        hr[5] = (_Float16)(sa2f * s1.x + ca2 * s1.y);
        hr[6] = (_Float16)(ca3 * s1.z - sa3f * s1.w);
        hr[7] = (_Float16)(sa3f * s1.z + ca3 * s1.w);
        ho[0]=(_Float16)o0.x; ho[1]=(_Float16)o0.y; ho[2]=(_Float16)o0.z; ho[3]=(_Float16)o0.w;
        ho[4]=(_Float16)o1.x; ho[5]=(_Float16)o1.y; ho[6]=(_Float16)o1.z; ho[7]=(_Float16)o1.w;
        const int lq = wid * 4 + i;
        const int sw = (lane * 8) ^ ((lq & 7) << 3);
        *(f16x8*)(RTs + lq * 512 + sw) = hr;
        *(f16x8*)(OVs + lq * 512 + sw) = ho;
    }
    __syncthreads();

    // ---- phase B1: norms/dots via MFMA diag tiles (10 tasks over 8 waves) --
    switch (wid) {
        case 0: diag_gemm(RTs,  RTs,   0,  0, ssA,      lane);
                diag_gemm(RELs, RELs, 32, 32, uuA + 32, lane); break;
        case 1: diag_gemm(RTs,  RTs,  16, 16, ssA + 16, lane);
                diag_gemm(RELs, RELs, 48, 48, uuA + 48, lane); break;
        case 2: diag_gemm(OVs,  OVs,   0,  0, ooA,      lane); break;
        case 3: diag_gemm(OVs,  OVs,  16, 16, ooA + 16, lane); break;
        case 4: diag_gemm(RTs,  OVs,   0,  0, rwA,      lane); break;
        case 5: diag_gemm(RTs,  OVs,  16, 16, rwA + 16, lane); break;
        case 6: diag_gemm(RELs, RELs,  0,  0, uuA,      lane); break;
        case 7: diag_gemm(RELs, RELs, 16, 16, uuA + 16, lane); break;
    }
    __syncthreads();

    // ---- phase B2: scalar chains, 96-wide ----
    if (wid == 0 && lane < 32) {
        const float ss = ssA[lane], oo = ooA[lane], rw = rwA[lane];
        const float ls  = atanhc(c * ss);
        const float nu2 = ls * ls * ss;
        const float eq  = tanhc(c * nu2);
        const float rr  = eq * eq * nu2;
        const float ro  = eq * ls * rw;
        const float A1  = 1.0f - 2.0f * c * ro + c * oo;
        const float B1  = 1.0f - c * rr;
        const float den = fmaxf(1.0f - 2.0f * c * ro + c * c * rr * oo, 1e-15f);
        const float inv = 1.0f / den;
        qas[lane] = -A1 * eq * ls * inv;         // multiplies P1 = R(s).rel
        qbs[lane] = B1 * inv;                    // multiplies P2 = o.rel
        x2s[lane] = (A1 * A1 * rr - 2.0f * A1 * B1 * ro + B1 * B1 * oo) * inv * inv;
    } else if (wid == 1) {
        const float uu = uuA[lane];
        const float er = tanhc(c * uu);
        esn[lane] = er;
        y2n[lane] = er * er * uu;
    }
    __syncthreads();

    // ---- phase B3: dual GEMM (full K per wave) + fused epilogue ----
    const int wm = wid & 1, wn = wid >> 1;       // 2m x 4n wave grid
    const int r15 = lane & 15, kg = lane >> 4;
    const int rA = wm * 16 + r15;
    const int rB = wn * 16 + r15;
    const _Float16* pa1 = RTs + rA * 512;
    const _Float16* pa2 = OVs + rA * 512;
    const _Float16* pb  = RELs + rB * 512;
    const int xa = (rA & 7) << 3, xb = (rB & 7) << 3;

    f32x4 acc1 = {}, acc2 = {};
#pragma unroll
    for (int ks = 0; ks < 16; ++ks) {
        const int ko = ks * 32 + kg * 8;
        const f16x8 b  = *(const f16x8*)(pb + (ko ^ xb));
        const f16x8 a1 = *(const f16x8*)(pa1 + (ko ^ xa));
        const f16x8 a2 = *(const f16x8*)(pa2 + (ko ^ xa));
        acc1 = __builtin_amdgcn_mfma_f32_16x16x32_f16(a1, b, acc1, 0, 0, 0);
        acc2 = __builtin_amdgcn_mfma_f32_16x16x32_f16(a2, b, acc2, 0, 0, 0);
    }

    // epilogue: C/D layout col = lane&15, row = (lane>>4)*4 + reg
    const int crow = kg * 4, ccol = r15;
    const int nl = wn * 16 + ccol;
    const int n  = n0 + nl;
    const float er = esn[nl];
    const float Y2 = y2n[nl];
    const float bn = bias[n];
#pragma unroll
    for (int r = 0; r < 4; ++r) {
        const int ml = wm * 16 + crow + r;
        const float qd = er * (qas[ml] * acc1[r] + qbs[ml] * acc2[r]);
        const float X2 = x2s[ml];
        const float B1 = 1.0f - c * X2;
        const float A1  = 1.0f - 2.0f * c * qd + c * Y2;
        const float den = fmaxf(1.0f - 2.0f * c * qd + c * c * X2 * Y2, 1e-15f);
        const float num2 = A1 * A1 * X2 - 2.0f * A1 * B1 * qd + B1 * B1 * Y2;
        out[(size_t)(m0 + ml) * NREL + n] = -(num2 / (den * den)) + bn;
    }
}

extern "C" void kernel_launch(void* const* d_in, const int* in_sizes, int n_in,
                              void* d_out, int out_size, void* d_ws, size_t ws_size,
                              hipStream_t stream) {
    const float* ent  = (const float*)d_in[0];   // (20000, 512)
    const float* rel  = (const float*)d_in[1];   // (512, 512)
    const int*   trip = (const int*)d_in[2];     // (1024, 3)
    const float* grot = (const float*)d_in[3];   // (256,)
    const float* bias = (const float*)d_in[4];   // (512,)
    float* out = (float*)d_out;                  // (1024, 512)

    const size_t shmem = (size_t)(64 * 512 + 32 * 512 + 32 * 512) * sizeof(_Float16)
                       + (size_t)(32 * 6 + 64 * 3) * sizeof(float);   // ~129.5 KB
    fused_kernel<<<dim3(256), dim3(512), shmem, stream>>>(
        ent, rel, trip, grot, bias, out);
}

// Round 18
// 11.768 us; speedup vs baseline: 1.0165x; 1.0165x over previous
//
#include <hip/hip_runtime.h>
#include <math.h>

#define D 512
#define NREL 512
#define NB 1024

typedef _Float16 f16x8 __attribute__((ext_vector_type(8)));
typedef float f32x4 __attribute__((ext_vector_type(4)));

// tanh(x)/x and atanh(x)/x as even polynomials in u = x^2 (x <= ~0.05 here;
// truncation error < 1e-8, fp32-exact).
__device__ __forceinline__ float tanhc(float u) {
    return 1.0f + u * (-0.33333333f + u * (0.13333333f - u * 0.05396825f));
}
__device__ __forceinline__ float atanhc(float u) {
    return 1.0f + u * (0.33333333f + u * (0.2f + u * 0.14285714f));
}

// diag of one 16x16 tile of (Arows · Brows^T), K = 512, XOR-swizzled LDS rows.
// C/D layout: col = lane&15, row = (lane>>4)*4 + reg  ->  lane holds diag elem
// (col) iff (col>>2) == (lane>>4); that elem is acc[col&3].
__device__ __forceinline__ void diag_gemm(
        const _Float16* __restrict__ Abase, const _Float16* __restrict__ Bbase,
        int rowA, int rowB, float* __restrict__ dst, int lane) {
    const int r15 = lane & 15, kg = lane >> 4;
    const _Float16* pa = Abase + (size_t)(rowA + r15) * 512;
    const _Float16* pb = Bbase + (size_t)(rowB + r15) * 512;
    const int xa = ((rowA + r15) & 7) << 3;
    const int xb = ((rowB + r15) & 7) << 3;
    f32x4 acc = {};
#pragma unroll
    for (int ks = 0; ks < 16; ++ks) {
        const int ko = ks * 32 + kg * 8;
        const f16x8 a = *(const f16x8*)(pa + (ko ^ xa));
        const f16x8 b = *(const f16x8*)(pb + (ko ^ xb));
        acc = __builtin_amdgcn_mfma_f32_16x16x32_f16(a, b, acc, 0, 0, 0);
    }
    if ((r15 >> 2) == kg) dst[r15] = acc[r15 & 3];
}

// Single dispatch, 256 blocks (1/CU), 512 threads. Block = 32m x 64n tile.
// Phase A: stage RAW fp16 (rel, R(s), o) -> swizzled LDS.
// Then (one region, no barrier between): B1 diag norms + main dual GEMM —
// the GEMM does not depend on B1, so diag stragglers hide behind MFMAs.
// sync -> B2 scalar chains -> sync -> epilogue.
__global__ __launch_bounds__(512, 1) void fused_kernel(
        const float* __restrict__ ent, const float* __restrict__ rel,
        const int* __restrict__ trip, const float* __restrict__ grot,
        const float* __restrict__ bias, float* __restrict__ out) {
    extern __shared__ char smem[];
    _Float16* RELs = (_Float16*)smem;            // 64 x 512 fp16 raw (swz)
    _Float16* RTs  = RELs + 64 * 512;            // 32 x 512 fp16 R(s) (swz)
    _Float16* OVs  = RTs + 32 * 512;             // 32 x 512 fp16 o    (swz)
    float* ssA = (float*)(OVs + 32 * 512);       // 32
    float* ooA = ssA + 32;                       // 32
    float* rwA = ooA + 32;                       // 32
    float* uuA = rwA + 32;                       // 64
    float* qas = uuA + 64;                       // 32
    float* qbs = qas + 32;                       // 32
    float* x2s = qbs + 32;                       // 32
    float* esn = x2s + 32;                       // 64
    float* y2n = esn + 64;                       // 64

    const int t = threadIdx.x, wid = t >> 6, lane = t & 63;
    // XCD swizzle (R14-proven): xcd = bid%8 owns a 4n x 8m region
    const int bid = blockIdx.x;
    const int xcd = bid & 7, slot = bid >> 3;
    const int nx  = (xcd & 1) * 4 + (slot & 3);
    const int my  = (xcd >> 1) * 8 + (slot >> 2);
    const int n0 = nx * 64, m0 = my * 32;
    const float c = 0.01f;

    // ---- trip indices first (they gate the ent gather) ----
    int si[4], oi[4];
#pragma unroll
    for (int i = 0; i < 4; ++i) {
        const int b = m0 + wid * 4 + i;
        si[i] = trip[3 * b];
        oi[i] = trip[3 * b + 2];
    }

    // ---- rel: 8 rows/wave -> raw fp16 to LDS ----
#pragma unroll
    for (int j = 0; j < 8; ++j) {
        const int lr = wid * 8 + j;
        const float4 a0 = *(const float4*)(rel + (size_t)(n0 + lr) * D + lane * 8);
        const float4 a1 = *(const float4*)(rel + (size_t)(n0 + lr) * D + lane * 8 + 4);
        f16x8 h;
        h[0]=(_Float16)a0.x; h[1]=(_Float16)a0.y; h[2]=(_Float16)a0.z; h[3]=(_Float16)a0.w;
        h[4]=(_Float16)a1.x; h[5]=(_Float16)a1.y; h[6]=(_Float16)a1.z; h[7]=(_Float16)a1.w;
        *(f16x8*)(RELs + lr * 512 + ((lane * 8) ^ ((lr & 7) << 3))) = h;
    }

    // ---- q: 4 rows/wave -> rotate raw s; stage R(s), o ----
    const float4 ang = *(const float4*)(grot + 4 * lane);
    const float ca0 = __cosf(ang.x), sa0 = __sinf(ang.x);
    const float ca1 = __cosf(ang.y), sa1 = __sinf(ang.y);
    const float ca2 = __cosf(ang.z), sa2 = __sinf(ang.z);
    const float ca3 = __cosf(ang.w), sa3 = __sinf(ang.w);
#pragma unroll
    for (int i = 0; i < 4; ++i) {
        const float4 s0 = *(const float4*)(ent + (size_t)si[i] * D + lane * 8);
        const float4 s1 = *(const float4*)(ent + (size_t)si[i] * D + lane * 8 + 4);
        const float4 o0 = *(const float4*)(ent + (size_t)oi[i] * D + lane * 8);
        const float4 o1 = *(const float4*)(ent + (size_t)oi[i] * D + lane * 8 + 4);
        f16x8 hr, ho;
        hr[0] = (_Float16)(ca0 * s0.x - sa0 * s0.y);
        hr[1] = (_Float16)(sa0 * s0.x + ca0 * s0.y);
        hr[2] = (_Float16)(ca1 * s0.z - sa1 * s0.w);
        hr[3] = (_Float16)(sa1 * s0.z + ca1 * s0.w);
        hr[4] = (_Float16)(ca2 * s1.x - sa2 * s1.y);
        hr[5] = (_Float16)(sa2 * s1.x + ca2 * s1.y);
        hr[6] = (_Float16)(ca3 * s1.z - sa3 * s1.w);
        hr[7] = (_Float16)(sa3 * s1.z + ca3 * s1.w);
        ho[0]=(_Float16)o0.x; ho[1]=(_Float16)o0.y; ho[2]=(_Float16)o0.z; ho[3]=(_Float16)o0.w;
        ho[4]=(_Float16)o1.x; ho[5]=(_Float16)o1.y; ho[6]=(_Float16)o1.z; ho[7]=(_Float16)o1.w;
        const int lq = wid * 4 + i;
        const int sw = (lane * 8) ^ ((lq & 7) << 3);
        *(f16x8*)(RTs + lq * 512 + sw) = hr;
        *(f16x8*)(OVs + lq * 512 + sw) = ho;
    }
    __syncthreads();

    // ---- B1: norms/dots via MFMA diag tiles (no barrier after — the main
    //      GEMM below is independent of these results) ----
    switch (wid) {
        case 0: diag_gemm(RTs,  RTs,   0,  0, ssA,      lane);
                diag_gemm(RELs, RELs, 32, 32, uuA + 32, lane); break;
        case 1: diag_gemm(RTs,  RTs,  16, 16, ssA + 16, lane);
                diag_gemm(RELs, RELs, 48, 48, uuA + 48, lane); break;
        case 2: diag_gemm(OVs,  OVs,   0,  0, ooA,      lane); break;
        case 3: diag_gemm(OVs,  OVs,  16, 16, ooA + 16, lane); break;
        case 4: diag_gemm(RTs,  OVs,   0,  0, rwA,      lane); break;
        case 5: diag_gemm(RTs,  OVs,  16, 16, rwA + 16, lane); break;
        case 6: diag_gemm(RELs, RELs,  0,  0, uuA,      lane); break;
        case 7: diag_gemm(RELs, RELs, 16, 16, uuA + 16, lane); break;
    }

    // ---- main dual GEMM (reads only phase-A LDS; overlaps B1 stragglers) --
    const int wm = wid & 1, wn = wid >> 1;       // 2m x 4n wave grid
    const int r15 = lane & 15, kg = lane >> 4;
    const int rA = wm * 16 + r15;
    const int rB = wn * 16 + r15;
    const _Float16* pa1 = RTs + rA * 512;
    const _Float16* pa2 = OVs + rA * 512;
    const _Float16* pb  = RELs + rB * 512;
    const int xa = (rA & 7) << 3, xb = (rB & 7) << 3;

    f32x4 acc1 = {}, acc2 = {};
#pragma unroll
    for (int ks = 0; ks < 16; ++ks) {
        const int ko = ks * 32 + kg * 8;
        const f16x8 b  = *(const f16x8*)(pb + (ko ^ xb));
        const f16x8 a1 = *(const f16x8*)(pa1 + (ko ^ xa));
        const f16x8 a2 = *(const f16x8*)(pa2 + (ko ^ xa));
        acc1 = __builtin_amdgcn_mfma_f32_16x16x32_f16(a1, b, acc1, 0, 0, 0);
        acc2 = __builtin_amdgcn_mfma_f32_16x16x32_f16(a2, b, acc2, 0, 0, 0);
    }
    __syncthreads();                             // B1 results now visible

    // ---- B2: scalar chains, 96-wide ----
    if (wid == 0 && lane < 32) {
        const float ss = ssA[lane], oo = ooA[lane], rw = rwA[lane];
        const float ls  = atanhc(c * ss);
        const float nu2 = ls * ls * ss;
        const float eq  = tanhc(c * nu2);
        const float rr  = eq * eq * nu2;
        const float ro  = eq * ls * rw;
        const float A1  = 1.0f - 2.0f * c * ro + c * oo;
        const float B1  = 1.0f - c * rr;
        const float den = fmaxf(1.0f - 2.0f * c * ro + c * c * rr * oo, 1e-15f);
        const float inv = 1.0f / den;
        qas[lane] = -A1 * eq * ls * inv;         // multiplies P1 = R(s).rel
        qbs[lane] = B1 * inv;                    // multiplies P2 = o.rel
        x2s[lane] = (A1 * A1 * rr - 2.0f * A1 * B1 * ro + B1 * B1 * oo) * inv * inv;
    } else if (wid == 1) {
        const float uu = uuA[lane];
        const float er = tanhc(c * uu);
        esn[lane] = er;
        y2n[lane] = er * er * uu;
    }
    __syncthreads();

    // ---- epilogue: C/D layout col = lane&15, row = (lane>>4)*4 + reg ----
    const int crow = kg * 4, ccol = r15;
    const int nl = wn * 16 + ccol;
    const int n  = n0 + nl;
    const float er = esn[nl];
    const float Y2 = y2n[nl];
    const float bn = bias[n];
#pragma unroll
    for (int r = 0; r < 4; ++r) {
        const int ml = wm * 16 + crow + r;
        const float qd = er * (qas[ml] * acc1[r] + qbs[ml] * acc2[r]);
        const float X2 = x2s[ml];
        const float B1 = 1.0f - c * X2;
        const float A1  = 1.0f - 2.0f * c * qd + c * Y2;
        const float den = fmaxf(1.0f - 2.0f * c * qd + c * c * X2 * Y2, 1e-15f);
        const float num2 = A1 * A1 * X2 - 2.0f * A1 * B1 * qd + B1 * B1 * Y2;
        out[(size_t)(m0 + ml) * NREL + n] = -(num2 / (den * den)) + bn;
    }
}

extern "C" void kernel_launch(void* const* d_in, const int* in_sizes, int n_in,
                              void* d_out, int out_size, void* d_ws, size_t ws_size,
                              hipStream_t stream) {
    const float* ent  = (const float*)d_in[0];   // (20000, 512)
    const float* rel  = (const float*)d_in[1];   // (512, 512)
    const int*   trip = (const int*)d_in[2];     // (1024, 3)
    const float* grot = (const float*)d_in[3];   // (256,)
    const float* bias = (const float*)d_in[4];   // (512,)
    float* out = (float*)d_out;                  // (1024, 512)

    const size_t shmem = (size_t)(64 * 512 + 32 * 512 + 32 * 512) * sizeof(_Float16)
                       + (size_t)(32 * 6 + 64 * 3) * sizeof(float);   // ~129.5 KB
    fused_kernel<<<dim3(256), dim3(512), shmem, stream>>>(
        ent, rel, trip, grot, bias, out);
}